// Round 1
// baseline (441.827 us; speedup 1.0000x reference)
//
#include <hip/hip_runtime.h>
#include <hip/hip_bf16.h>
#include <cstdint>

// DistanceAwareSelfAttention: SLEN=1024, BSZ=8, H=16, D=64, EMB=1024, CLIP=10
// Pipeline: f2b converts -> GEMM1 (in_proj, scatter to (3,b,h,s,d)) -> vtrans
//           -> qk band-bias table -> flash attention (+band corrections) -> GEMM2 (out_proj)

typedef __attribute__((ext_vector_type(8))) __bf16 bf16x8;
typedef __attribute__((ext_vector_type(4))) __bf16 bf16x4;
typedef __attribute__((ext_vector_type(4))) float f32x4;

__device__ __forceinline__ void gload_lds16(const void* g, void* l) {
  __builtin_amdgcn_global_load_lds(
      (const __attribute__((address_space(1))) void*)g,
      (__attribute__((address_space(3))) void*)l, 16, 0, 0);
}

__global__ __launch_bounds__(256) void f2b_kernel(const float* __restrict__ src,
                                                  __bf16* __restrict__ dst, int n) {
  int i = (blockIdx.x * 256 + threadIdx.x) * 8;
  if (i >= n) return;
  float4 a = *(const float4*)(src + i);
  float4 b = *(const float4*)(src + i + 4);
  bf16x8 o;
  o[0] = (__bf16)a.x; o[1] = (__bf16)a.y; o[2] = (__bf16)a.z; o[3] = (__bf16)a.w;
  o[4] = (__bf16)b.x; o[5] = (__bf16)b.y; o[6] = (__bf16)b.z; o[7] = (__bf16)b.w;
  *(bf16x8*)(dst + i) = o;
}

// C[m][n] = sum_k A[m][k]*B[n][k] + bias[n].  128x128 tile, BK=64, 4 waves.
// EPI 0: scatter bf16 to qkvt (3,b,h,s,d), scale q by 0.125.  EPI 1: fp32 out.
template <int EPI>
__global__ __launch_bounds__(256) void gemm_nt(
    const __bf16* __restrict__ A, const __bf16* __restrict__ B,
    const float* __restrict__ bias, int K,
    float* __restrict__ outF, __bf16* __restrict__ outT, int N) {
  __shared__ __align__(16) __bf16 sA[128 * 64];
  __shared__ __align__(16) __bf16 sB[128 * 64];
  const int tid = threadIdx.x;
  const int wave = tid >> 6, lane = tid & 63;
  const int lg = lane >> 4, lr = lane & 15;
  const int wr = wave >> 1, wc = wave & 1;
  const int m0 = blockIdx.y * 128;
  const int n0 = blockIdx.x * 128;

  f32x4 acc[4][4] = {};

  for (int kt = 0; kt < K; kt += 64) {
#pragma unroll
    for (int it = 0; it < 4; ++it) {
      int c = it * 256 + tid;
      int r = c >> 3, c8 = (c & 7) * 8;
      gload_lds16(A + (size_t)(m0 + r) * K + kt + c8,
                  (void*)&sA[(it * 256 + wave * 64) * 8]);
      gload_lds16(B + (size_t)(n0 + r) * K + kt + c8,
                  (void*)&sB[(it * 256 + wave * 64) * 8]);
    }
    __syncthreads();
#pragma unroll
    for (int kk = 0; kk < 2; ++kk) {
      bf16x8 af[4], bfr[4];
#pragma unroll
      for (int i = 0; i < 4; ++i)
        af[i] = *(const bf16x8*)&sA[(wr * 64 + i * 16 + lr) * 64 + kk * 32 + lg * 8];
#pragma unroll
      for (int j = 0; j < 4; ++j)
        bfr[j] = *(const bf16x8*)&sB[(wc * 64 + j * 16 + lr) * 64 + kk * 32 + lg * 8];
#pragma unroll
      for (int i = 0; i < 4; ++i)
#pragma unroll
        for (int j = 0; j < 4; ++j)
          acc[i][j] = __builtin_amdgcn_mfma_f32_16x16x32_bf16(af[i], bfr[j], acc[i][j], 0, 0, 0);
    }
    __syncthreads();
  }

#pragma unroll
  for (int i = 0; i < 4; ++i) {
    const int gm0 = m0 + wr * 64 + i * 16 + lg * 4;
#pragma unroll
    for (int j = 0; j < 4; ++j) {
      const int gn = n0 + wc * 64 + j * 16 + lr;
      const float bv = bias[gn];
#pragma unroll
      for (int rg = 0; rg < 4; ++rg) {
        const int gm = gm0 + rg;
        float v = acc[i][j][rg] + bv;
        if constexpr (EPI == 0) {
          int t = gn >> 10, h = (gn >> 6) & 15, d = gn & 63;
          int s = gm >> 3, b = gm & 7;
          if (t == 0) v *= 0.125f;  // q * d^-0.5
          outT[(((size_t)((t * 8 + b) * 16 + h) * 1024 + s) << 6) + d] = (__bf16)v;
        } else {
          outF[(size_t)gm * N + gn] = v;
        }
      }
    }
  }
}

// v (bh,s,d) -> vt (bh,d,s), 64x64 tiles
__global__ __launch_bounds__(256) void vtrans_kernel(const __bf16* __restrict__ v,
                                                     __bf16* __restrict__ vt) {
  __shared__ __bf16 tile[64][66];
  const int tid = threadIdx.x;
  const int bh = blockIdx.x >> 4;
  const int s0 = (blockIdx.x & 15) * 64;
  const __bf16* src = v + ((size_t)bh * 1024 + s0) * 64;
#pragma unroll
  for (int it = 0; it < 4; ++it) {
    int idx = it * 256 + tid;
    int r = idx >> 4, c4 = (idx & 15) * 4;
    bf16x4 x = *(const bf16x4*)&src[r * 64 + c4];
    tile[r][c4 + 0] = x[0]; tile[r][c4 + 1] = x[1];
    tile[r][c4 + 2] = x[2]; tile[r][c4 + 3] = x[3];
  }
  __syncthreads();
  __bf16* dst = vt + (size_t)bh * 65536;
#pragma unroll
  for (int it = 0; it < 4; ++it) {
    int idx = it * 256 + tid;
    int dr = idx >> 4, s4 = (idx & 15) * 4;
    bf16x4 y;
    y[0] = tile[s4 + 0][dr]; y[1] = tile[s4 + 1][dr];
    y[2] = tile[s4 + 2][dr]; y[3] = tile[s4 + 3][dr];
    *(bf16x4*)&dst[(size_t)dr * 1024 + s0 + s4] = y;
  }
}

// biasD[row][c] = q[row]·(kde[c]-kde[10]) for c<10, else 0.  row = bh*1024+s.
__global__ __launch_bounds__(256) void qkbias_kernel(const __bf16* __restrict__ q,
                                                     const float* __restrict__ kde,
                                                     float* __restrict__ biasD) {
  const int row = blockIdx.x * 16 + (threadIdx.x >> 4);
  const int c = threadIdx.x & 15;
  float acc = 0.f;
  if (c < 10) {
    const __bf16* qr = q + (size_t)row * 64;
#pragma unroll
    for (int d = 0; d < 64; ++d)
      acc += (float)qr[d] * (kde[c * 64 + d] - kde[640 + d]);
  }
  biasD[(size_t)row * 16 + c] = acc;
}

// Flash attention w/ distance band.  8 waves, 16 q-rows/wave (Q-tile 128), KV tiles of 64.
__global__ __launch_bounds__(512) void attn_kernel(
    const __bf16* __restrict__ qkv, const __bf16* __restrict__ vt,
    const float* __restrict__ biasD, const float* __restrict__ vde,
    __bf16* __restrict__ O) {
  __shared__ float band[8][16][20];            // band logits, slot = (t-s)+9
  __shared__ __align__(16) __bf16 pbuf[8][16][72];  // per-wave P transpose buffer
  const int tid = threadIdx.x, wave = tid >> 6, lane = tid & 63;
  const int lg = lane >> 4, lr = lane & 15;
  const int bh = blockIdx.x >> 3;
  const int stile = blockIdx.x & 7;
  const int sb = stile * 128 + wave * 16;
  const int b = bh >> 4, h = bh & 15;
  const __bf16* qp = qkv + (size_t)bh * 65536;
  const __bf16* kp = qkv + (size_t)(128 + bh) * 65536;
  const __bf16* vtp = vt + (size_t)bh * 65536;

  {
    float* bf = &band[0][0][0];
    for (int i = tid; i < 8 * 16 * 20; i += 512) bf[i] = -1e30f;
  }
  __syncthreads();

  bf16x8 aq[2];
#pragma unroll
  for (int kk = 0; kk < 2; ++kk)
    aq[kk] = *(const bf16x8*)&qp[(size_t)(sb + lr) * 64 + kk * 32 + lg * 8];

  f32x4 o_acc[4] = {};
  float mrow[4], lrow[4];
#pragma unroll
  for (int r = 0; r < 4; ++r) { mrow[r] = -1e30f; lrow[r] = 0.f; }

  for (int kt = 0; kt < 16; ++kt) {
    const int t0 = kt * 64;
    // ---- QK^T ----
    f32x4 sf[4];
#pragma unroll
    for (int tj = 0; tj < 4; ++tj) {
      bf16x8 bk0 = *(const bf16x8*)&kp[(size_t)(t0 + tj * 16 + lr) * 64 + lg * 8];
      bf16x8 bk1 = *(const bf16x8*)&kp[(size_t)(t0 + tj * 16 + lr) * 64 + 32 + lg * 8];
      f32x4 z = {};
      z = __builtin_amdgcn_mfma_f32_16x16x32_bf16(aq[0], bk0, z, 0, 0, 0);
      z = __builtin_amdgcn_mfma_f32_16x16x32_bf16(aq[1], bk1, z, 0, 0, 0);
      sf[tj] = z;
    }
    // ---- distance-band bias (softmax-invariant shift applied) ----
    const bool inband = (t0 <= sb + 24) && (t0 + 63 >= sb - 9);
    if (inband) {
#pragma unroll
      for (int tj = 0; tj < 4; ++tj) {
        const int t = t0 + tj * 16 + lr;
#pragma unroll
        for (int rg = 0; rg < 4; ++rg) {
          const int s = sb + lg * 4 + rg;
          const int dd = t - s;
          const int ad = dd < 0 ? -dd : dd;
          const int c = ad < 15 ? ad : 15;
          const float val = sf[tj][rg] + biasD[((size_t)bh * 1024 + s) * 16 + c];
          sf[tj][rg] = val;
          if (ad <= 9) band[wave][lg * 4 + rg][dd + 9] = val;
        }
      }
    }
    // ---- online softmax ----
    float vmax[4];
#pragma unroll
    for (int rg = 0; rg < 4; ++rg)
      vmax[rg] = fmaxf(fmaxf(sf[0][rg], sf[1][rg]), fmaxf(sf[2][rg], sf[3][rg]));
#pragma unroll
    for (int off = 1; off < 16; off <<= 1)
#pragma unroll
      for (int rg = 0; rg < 4; ++rg)
        vmax[rg] = fmaxf(vmax[rg], __shfl_xor(vmax[rg], off, 64));
    float scl[4];
#pragma unroll
    for (int rg = 0; rg < 4; ++rg) {
      float mn = fmaxf(mrow[rg], vmax[rg]);
      scl[rg] = __expf(mrow[rg] - mn);
      mrow[rg] = mn;
    }
    float rsum[4] = {0.f, 0.f, 0.f, 0.f};
#pragma unroll
    for (int tj = 0; tj < 4; ++tj)
#pragma unroll
      for (int rg = 0; rg < 4; ++rg) {
        float p = __expf(sf[tj][rg] - mrow[rg]);
        sf[tj][rg] = p;
        rsum[rg] += p;
      }
#pragma unroll
    for (int off = 1; off < 16; off <<= 1)
#pragma unroll
      for (int rg = 0; rg < 4; ++rg)
        rsum[rg] += __shfl_xor(rsum[rg], off, 64);
#pragma unroll
    for (int rg = 0; rg < 4; ++rg)
      lrow[rg] = lrow[rg] * scl[rg] + rsum[rg];
#pragma unroll
    for (int dj = 0; dj < 4; ++dj)
#pragma unroll
      for (int rg = 0; rg < 4; ++rg)
        o_acc[dj][rg] *= scl[rg];
    // ---- P -> LDS (lane transpose for PV A-operand) ----
#pragma unroll
    for (int tj = 0; tj < 4; ++tj)
#pragma unroll
      for (int rg = 0; rg < 4; ++rg)
        pbuf[wave][lg * 4 + rg][tj * 16 + lr] = (__bf16)sf[tj][rg];
    asm volatile("s_waitcnt lgkmcnt(0)" ::: "memory");
    __builtin_amdgcn_sched_barrier(0);
    // ---- PV ----
    bf16x8 pa[2];
#pragma unroll
    for (int kk = 0; kk < 2; ++kk)
      pa[kk] = *(const bf16x8*)&pbuf[wave][lr][kk * 32 + lg * 8];
#pragma unroll
    for (int dj = 0; dj < 4; ++dj) {
      bf16x8 bv0 = *(const bf16x8*)&vtp[(size_t)(dj * 16 + lr) * 1024 + t0 + lg * 8];
      bf16x8 bv1 = *(const bf16x8*)&vtp[(size_t)(dj * 16 + lr) * 1024 + t0 + 32 + lg * 8];
      o_acc[dj] = __builtin_amdgcn_mfma_f32_16x16x32_bf16(pa[0], bv0, o_acc[dj], 0, 0, 0);
      o_acc[dj] = __builtin_amdgcn_mfma_f32_16x16x32_bf16(pa[1], bv1, o_acc[dj], 0, 0, 0);
    }
  }

  // ---- epilogue: normalize + v_dist band correction, write (s,b,h*d) bf16 ----
#pragma unroll
  for (int rg = 0; rg < 4; ++rg) {
    const int rl = lg * 4 + rg;
    const int s = sb + rl;
    const float inv = 1.f / lrow[rg];
    float psum[10];
    psum[0] = __expf(band[wave][rl][9] - mrow[rg]);
#pragma unroll
    for (int c = 1; c < 10; ++c)
      psum[c] = __expf(band[wave][rl][9 - c] - mrow[rg]) +
                __expf(band[wave][rl][9 + c] - mrow[rg]);
#pragma unroll
    for (int dj = 0; dj < 4; ++dj) {
      const int d = dj * 16 + lr;
      float acc2 = 0.f;
#pragma unroll
      for (int c = 0; c < 10; ++c)
        acc2 += psum[c] * (vde[c * 64 + d] - vde[640 + d]);
      float val = (o_acc[dj][rg] + acc2) * inv + vde[640 + d];
      O[((size_t)(s * 8 + b)) * 1024 + h * 64 + d] = (__bf16)val;
    }
  }
}

extern "C" void kernel_launch(void* const* d_in, const int* in_sizes, int n_in,
                              void* d_out, int out_size, void* d_ws, size_t ws_size,
                              hipStream_t stream) {
  (void)in_sizes; (void)n_in; (void)out_size; (void)ws_size;
  const float* inputs = (const float*)d_in[0];
  const float* W_in   = (const float*)d_in[1];
  const float* b_in   = (const float*)d_in[2];
  const float* kde    = (const float*)d_in[3];
  const float* vde    = (const float*)d_in[4];
  const float* W_out  = (const float*)d_in[5];
  const float* b_out  = (const float*)d_in[6];
  float* out = (float*)d_out;

  char* ws = (char*)d_ws;
  __bf16* qkvt  = (__bf16*)(ws);              // (3,8,16,1024,64) bf16: 50331648 B
  __bf16* vt    = (__bf16*)(ws + 50331648);   // (128,64,1024)  bf16: 16777216 B
  float*  biasD = (float*) (ws + 67108864);   // (131072,16)    f32:   8388608 B
  __bf16* Xb    = (__bf16*)(ws + 75497472);   // (8192,1024)    bf16: 16777216 B
  __bf16* Ob    = (__bf16*)(ws + 75497472);   // reuse Xb region after GEMM1
  __bf16* Wb_in = (__bf16*)(ws + 92274688);   // (3072,1024)    bf16:  6291456 B
  __bf16* Wb_out= (__bf16*)(ws + 98566144);   // (1024,1024)    bf16:  2097152 B

  f2b_kernel<<<4096, 256, 0, stream>>>(inputs, Xb, 8388608);
  f2b_kernel<<<1536, 256, 0, stream>>>(W_in, Wb_in, 3145728);
  f2b_kernel<<<512, 256, 0, stream>>>(W_out, Wb_out, 1048576);

  gemm_nt<0><<<dim3(24, 64), 256, 0, stream>>>(Xb, Wb_in, b_in, 1024, nullptr, qkvt, 3072);
  vtrans_kernel<<<2048, 256, 0, stream>>>(qkvt + (size_t)2 * 128 * 65536, vt);
  qkbias_kernel<<<8192, 256, 0, stream>>>(qkvt, kde, biasD);
  attn_kernel<<<1024, 512, 0, stream>>>(qkvt, vt, biasD, vde, Ob);
  gemm_nt<1><<<dim3(8, 64), 256, 0, stream>>>(Ob, Wb_out, b_out, 1024, out, nullptr, 1024);
}